// Round 1
// baseline (245.808 us; speedup 1.0000x reference)
//
#include <hip/hip_runtime.h>

#define N_NODES 100000
#define N_EDGES 1600000
#define IN_DIM  128
#define C1      64     // hidden = 4 heads * 16
#define H1      4
#define F1      16
#define C2      16
#define NEG     0.2f
#define EPS_    1e-9f

#define NHB     256            // hist blocks (and matrix columns)
#define EPB     (N_EDGES/NHB)  // 6250 edges per hist/p1 block
#define G1B     391            // gemm1 blocks in fused kernel
#define NBUCK   196            // ceil(100000/512) non-empty buckets

typedef _Float16 half8 __attribute__((ext_vector_type(8)));
typedef _Float16 half4 __attribute__((ext_vector_type(4)));
typedef float float4v __attribute__((ext_vector_type(4)));

__device__ __forceinline__ float lrelu(float x) { return x > 0.f ? x : NEG * x; }

// ================= k_h1g: layer-1 GEMM (MFMA, LDS-built WT1) + bucket hist =================
// Blocks 0..G1B-1: gemm (16 waves x 16 nodes), WT1 built in LDS.
// Blocks G1B..G1B+255: LDS histogram of recv>>9 into M[bin][hb]. No global atomics.

__global__ __launch_bounds__(1024) void k_h1g(
    const float* __restrict__ x, const float* __restrict__ W1,
    const float* __restrict__ a1s, const float* __restrict__ a1d,
    _Float16* __restrict__ h1, _Float16* __restrict__ ssh, float* __restrict__ sd,
    const int* __restrict__ recv, int* __restrict__ M) {
  __shared__ _Float16 WT1L[80 * 136];   // rows 0-63 W1cat^T, 64-71 fused a-vecs; +8 pad
  __shared__ int hc[NHB];
  int b = blockIdx.x, t = threadIdx.x;

  if (b >= G1B) {                       // ---- histogram part ----
    int hb = b - G1B;
    if (t < NHB) hc[t] = 0;
    __syncthreads();
    int e1 = (hb + 1) * EPB;
    for (int e = hb * EPB + t; e < e1; e += 1024)
      atomicAdd(&hc[recv[e] >> 9], 1);  // LDS atomic
    __syncthreads();
    if (t < NHB) M[t * NHB + hb] = hc[t];
    return;
  }

  // ---- build WT1 in LDS ----
  for (int i = t; i < 80 * 128; i += 1024) {
    int c = i >> 7, k = i & 127;
    float v;
    if (c < 64) v = W1[(c >> 4) * 2048 + k * 16 + (c & 15)];
    else {
      int h = (c - 64) & 3;
      const float* a = (c < 68) ? a1s : a1d;
      float s = 0.f;
      for (int f = 0; f < 16; ++f) s += W1[h * 2048 + k * 16 + f] * a[h * 16 + f];
      v = s;
    }
    WT1L[c * 136 + k] = (_Float16)v;
  }
  __syncthreads();

  int wave = b * 16 + (t >> 6);
  int n0 = wave * 16;
  if (n0 >= N_NODES) return;
  int lane = t & 63;
  int mrow = lane & 15, quad = lane >> 4;
  const float* xrow = x + (size_t)(n0 + mrow) * IN_DIM + quad * 8;
  float4v acc[5];
#pragma unroll
  for (int i = 0; i < 5; ++i) acc[i] = (float4v)(0.f);
#pragma unroll
  for (int kt = 0; kt < 4; ++kt) {
    float4 a0 = *(const float4*)(xrow + kt * 32);
    float4 a1 = *(const float4*)(xrow + kt * 32 + 4);
    half8 af;
    af[0] = (_Float16)a0.x; af[1] = (_Float16)a0.y; af[2] = (_Float16)a0.z; af[3] = (_Float16)a0.w;
    af[4] = (_Float16)a1.x; af[5] = (_Float16)a1.y; af[6] = (_Float16)a1.z; af[7] = (_Float16)a1.w;
#pragma unroll
    for (int i = 0; i < 5; ++i) {
      half8 bf = *(const half8*)(WT1L + (i * 16 + mrow) * 136 + kt * 32 + quad * 8);
      acc[i] = __builtin_amdgcn_mfma_f32_16x16x32_f16(af, bf, acc[i], 0, 0, 0);
    }
  }
#pragma unroll
  for (int i = 0; i < 4; ++i)
#pragma unroll
    for (int r = 0; r < 4; ++r)
      h1[(size_t)(n0 + quad * 4 + r) * C1 + i * 16 + mrow] = (_Float16)acc[i][r];
  if (mrow < 8) {
#pragma unroll
    for (int r = 0; r < 4; ++r) {
      int n = n0 + quad * 4 + r;
      float v = acc[4][r];
      if (mrow < 4) ssh[n * 4 + mrow] = (_Float16)v;
      else          sd[n * 4 + (mrow - 4)] = v;
    }
  }
}

// ================= k_p1s: fused coalesced matrix-scan + edge placement =================

__global__ __launch_bounds__(1024) void k_p1s(
    const int* __restrict__ recv, const int* __restrict__ send,
    const int* __restrict__ M, unsigned* __restrict__ tmp, int* __restrict__ bstart) {
  __shared__ int rsum[NHB], rpart[NHB], rscan[NHB], cur[NHB];
  int blk = blockIdx.x, t = threadIdx.x;
  int wv = t >> 6, l = t & 63;
  for (int pass = 0; pass < 16; ++pass) {     // 16 waves x 16 passes = 256 rows
    int row = pass * 16 + wv;
    int s = 0, p = 0;
#pragma unroll
    for (int c4 = 0; c4 < 4; ++c4) {
      int col = c4 * 64 + l;
      int v = M[row * NHB + col];
      s += v;
      p += (col < blk) ? v : 0;
    }
#pragma unroll
    for (int off = 1; off < 64; off <<= 1) {
      s += __shfl_xor(s, off);
      p += __shfl_xor(p, off);
    }
    if (l == 0) { rsum[row] = s; rpart[row] = p; }
  }
  __syncthreads();
  if (t < 64) {                               // exclusive scan of 256 rowsums
    int a0 = rsum[4 * t], a1 = rsum[4 * t + 1], a2 = rsum[4 * t + 2], a3 = rsum[4 * t + 3];
    int tot = a0 + a1 + a2 + a3, sc = tot;
#pragma unroll
    for (int off = 1; off < 64; off <<= 1) { int u = __shfl_up(sc, off); if (t >= off) sc += u; }
    int ex = sc - tot;
    rscan[4 * t] = ex; rscan[4 * t + 1] = ex + a0;
    rscan[4 * t + 2] = ex + a0 + a1; rscan[4 * t + 3] = ex + a0 + a1 + a2;
  }
  __syncthreads();
  if (t < NHB) cur[t] = rscan[t] + rpart[t];
  if (blk == 0 && t < NHB) bstart[t] = rscan[t];
  if (blk == 0 && t == 0) bstart[NHB] = N_EDGES;
  __syncthreads();
  int e1 = (blk + 1) * EPB;
  for (int e = blk * EPB + t; e < e1; e += 1024) {
    int r = recv[e], s = send[e];
    int pos = atomicAdd(&cur[r >> 9], 1);     // LDS returning atomic
    tmp[pos] = ((unsigned)(r & 511) << 17) | (unsigned)s;
  }
}

// ================= p2: per-bucket counting sort -> rs + csr =================

__global__ __launch_bounds__(1024) void k_p2(
    const int* __restrict__ bstart, const unsigned* __restrict__ tmp,
    int* __restrict__ rs, int* __restrict__ csr) {
  __shared__ int cnt[512];
  __shared__ int wt[8];
  int b = blockIdx.x, t = threadIdx.x;
  int e0 = bstart[b];
  int e1 = bstart[b + 1];
  if (t < 512) cnt[t] = 0;
  __syncthreads();
  for (int e = e0 + t; e < e1; e += 1024)
    atomicAdd(&cnt[tmp[e] >> 17], 1);
  __syncthreads();
  int v = (t < 512) ? cnt[t] : 0;
  int l = t & 63, s = v;
#pragma unroll
  for (int off = 1; off < 64; off <<= 1) { int u = __shfl_up(s, off); if (l >= off) s += u; }
  if (t < 512 && l == 63) wt[t >> 6] = s;
  __syncthreads();
  if (t < 8) {
    int p = wt[t];
#pragma unroll
    for (int off = 1; off < 8; off <<= 1) { int u = __shfl_up(p, off); if (t >= off) p += u; }
    wt[t] = p;
  }
  __syncthreads();
  int base = (t >= 64 && t < 512) ? wt[(t >> 6) - 1] : 0;
  int excl = e0 + base + s - v;
  int idx = b * 512 + t;
  if (t < 512 && idx <= N_NODES) rs[idx] = excl;
  __syncthreads();
  if (t < 512) cnt[t] = excl;
  __syncthreads();
  for (int e = e0 + t; e < e1; e += 1024) {
    unsigned u = tmp[e];
    int pos = atomicAdd(&cnt[u >> 17], 1);
    csr[pos] = (int)(u & 0x1FFFFu);
  }
}

// ================= k_agg1: layer-1 aggregation =================
// R10 restructure: 8 lanes/edge (g=lane>>3), half8 (16B) h1 loads, 8-edge chunks.
//  - per 8-edge chunk each lane: 1 csr load, 1 ssh gather, 1 exp path, 8 fma_mix
//    (vs 4x each per 16-edge chunk before) -> ~half the per-edge overhead VALU.
//  - chunk waste E[ceil(deg/8)]*8/deg ~= 1.22 vs 1.43 at chunk 16 (deg~Poisson(16)).
//  - epilogue: 9 values x 3 xor stages; lane g==0 writes half8 (coalesced 128B/wave).

__global__ __launch_bounds__(256) void k_agg1(
    const int* __restrict__ rs, const int* __restrict__ csr,
    const _Float16* __restrict__ ssh, const float* __restrict__ sdst,
    const _Float16* __restrict__ h1, _Float16* __restrict__ z) {
  int wid = (blockIdx.x * 256 + threadIdx.x) >> 6;
  if (wid >= N_NODES) return;
  int lane = threadIdx.x & 63;
  int g = lane >> 3;          // edge slot 0..7
  int f8 = lane & 7;          // feature block: feats [f8*8, f8*8+8)
  int h = f8 >> 1;            // head for this feature block
  int start = rs[wid], deg = rs[wid + 1] - start;
  float sdh = sdst[wid * 4 + h];
  float acc[8];
#pragma unroll
  for (int i = 0; i < 8; ++i) acc[i] = 0.f;
  float dsum = 0.f;
  const _Float16* hbase = h1 + f8 * 8;
  for (int j0 = 0; j0 < deg; j0 += 8) {
    int j = j0 + g;
    int s = csr[start + (j < deg ? j : 0)];
    float e = (float)ssh[s * 4 + h];
    half8 hv = *(const half8*)(hbase + (size_t)s * C1);
    float al = (j < deg) ? __expf(lrelu(e + sdh)) : 0.f;
    dsum += al;
#pragma unroll
    for (int i = 0; i < 8; ++i) acc[i] = fmaf(al, (float)hv[i], acc[i]);
  }
#pragma unroll
  for (int off = 8; off <= 32; off <<= 1) {
#pragma unroll
    for (int i = 0; i < 8; ++i) acc[i] += __shfl_xor(acc[i], off);
    dsum += __shfl_xor(dsum, off);
  }
  if (g == 0) {
    float inv = 1.f / (dsum + EPS_);
    half8 o;
#pragma unroll
    for (int i = 0; i < 8; ++i) {
      float v = acc[i] * inv;
      o[i] = (_Float16)(v > 0.f ? v : __expf(v) - 1.f);
    }
    *(half8*)(z + (size_t)wid * C1 + f8 * 8) = o;
  }
}

// ================= k_gemm2: MFMA, WT2 built in LDS (rows 18-31 zero) =================

__global__ __launch_bounds__(256) void k_gemm2(
    const _Float16* __restrict__ z, const float* __restrict__ W2,
    const float* __restrict__ a2s, const float* __restrict__ a2d,
    _Float16* __restrict__ h2, float* __restrict__ ss2, float* __restrict__ sd2) {
  __shared__ _Float16 WT2L[32 * 64];
  int t = threadIdx.x;
  for (int i = t; i < 32 * 64; i += 256) {
    int c = i >> 6, k = i & 63;
    float v = 0.f;
    if (c < 16) v = W2[k * 16 + c];
    else if (c == 16) { for (int f = 0; f < 16; ++f) v += W2[k * 16 + f] * a2s[f]; }
    else if (c == 17) { for (int f = 0; f < 16; ++f) v += W2[k * 16 + f] * a2d[f]; }
    WT2L[i] = (_Float16)v;
  }
  __syncthreads();
  int wave = blockIdx.x * 4 + (t >> 6);
  int n0 = wave * 16;
  if (n0 >= N_NODES) return;
  int lane = t & 63;
  int mrow = lane & 15, quad = lane >> 4;
  float4v acc0 = (float4v)(0.f), acc1 = (float4v)(0.f);
#pragma unroll
  for (int kt = 0; kt < 2; ++kt) {
    half8 af = *(const half8*)(z + (size_t)(n0 + mrow) * C1 + kt * 32 + quad * 8);
    half8 b0 = *(const half8*)(WT2L + (0 * 16 + mrow) * C1 + kt * 32 + quad * 8);
    half8 b1 = *(const half8*)(WT2L + (1 * 16 + mrow) * C1 + kt * 32 + quad * 8);
    acc0 = __builtin_amdgcn_mfma_f32_16x16x32_f16(af, b0, acc0, 0, 0, 0);
    acc1 = __builtin_amdgcn_mfma_f32_16x16x32_f16(af, b1, acc1, 0, 0, 0);
  }
#pragma unroll
  for (int r = 0; r < 4; ++r)
    h2[(size_t)(n0 + quad * 4 + r) * C2 + mrow] = (_Float16)acc0[r];
  if (mrow == 0) {
#pragma unroll
    for (int r = 0; r < 4; ++r) ss2[n0 + quad * 4 + r] = acc1[r];
  } else if (mrow == 1) {
#pragma unroll
    for (int r = 0; r < 4; ++r) sd2[n0 + quad * 4 + r] = acc1[r];
  }
}

// ================= k_agg2: layer-2 aggregation =================
// R10 restructure: 16 edges in flight, one edge per lane slot (g=lane>>2, q=lane&3).
// Kills the 2x predicated waste of the old 32-slot scheme (deg~Poisson(16):
// E[slots/edge] 2.06 -> 1.43) and halves per-edge overhead ops.

__global__ __launch_bounds__(256) void k_agg2(
    const int* __restrict__ rs, const int* __restrict__ csr,
    const float* __restrict__ ss2, const float* __restrict__ sd2,
    const _Float16* __restrict__ h2, float* __restrict__ out) {
  int wid = (blockIdx.x * 256 + threadIdx.x) >> 6;
  if (wid >= N_NODES) return;
  int lane = threadIdx.x & 63;
  int g = lane >> 2, q = lane & 3;
  int start = rs[wid], deg = rs[wid + 1] - start;
  float sd = sd2[wid];
  float a0 = 0.f, a1 = 0.f, a2 = 0.f, a3 = 0.f, dsum = 0.f;
  const _Float16* hbase = h2 + q * 4;
  for (int j0 = 0; j0 < deg; j0 += 16) {
    int j = j0 + g;
    int s = csr[start + (j < deg ? j : 0)];
    float e = ss2[s];
    half4 hv = *(const half4*)(hbase + (size_t)s * C2);
    float al = (j < deg) ? __expf(lrelu(e + sd)) : 0.f;
    dsum += al;
    a0 = fmaf(al, (float)hv[0], a0);
    a1 = fmaf(al, (float)hv[1], a1);
    a2 = fmaf(al, (float)hv[2], a2);
    a3 = fmaf(al, (float)hv[3], a3);
  }
#pragma unroll
  for (int off = 4; off <= 32; off <<= 1) {
    a0 += __shfl_xor(a0, off); a1 += __shfl_xor(a1, off);
    a2 += __shfl_xor(a2, off); a3 += __shfl_xor(a3, off);
    dsum += __shfl_xor(dsum, off);
  }
  if (g == 0) {
    float inv = 1.f / (dsum + EPS_);
    float4 o = make_float4(a0 * inv, a1 * inv, a2 * inv, a3 * inv);
    *(float4*)(out + (size_t)wid * C2 + q * 4) = o;
  }
}

// ================= launch: 6 dispatches =================

extern "C" void kernel_launch(void* const* d_in, const int* in_sizes, int n_in,
                              void* d_out, int out_size, void* d_ws, size_t ws_size,
                              hipStream_t stream) {
  const float* x    = (const float*)d_in[0];
  const int* senders   = (const int*)d_in[1];
  const int* receivers = (const int*)d_in[2];
  const float* W1  = (const float*)d_in[3];
  const float* a1s = (const float*)d_in[4];
  const float* a1d = (const float*)d_in[5];
  const float* W2  = (const float*)d_in[6];
  const float* a2s = (const float*)d_in[7];
  const float* a2d = (const float*)d_in[8];
  float* out = (float*)d_out;

  char* w = (char*)d_ws;
  _Float16* h1   = (_Float16*)(w + 0);          // 12,800,000 B [N][64]
  _Float16* z    = (_Float16*)(w + 12800000);   // 12,800,000 B
  _Float16* ssh1 = (_Float16*)(w + 25600000);   //    800,000 B [N][4]
  float* sd1 = (float*)(w + 26400000);          //  1,600,000 B [N][4]
  _Float16* h2   = (_Float16*)(w + 28000000);   //  3,200,000 B [N][16]
  float* ss2 = (float*)(w + 31200000);          //    400,000 B [N]
  float* sd2 = (float*)(w + 31600000);          //    400,000 B [N]
  int*   rs  = (int*)  (w + 32000000);          //    400,128 B [N+1]
  int*   csr = (int*)  (w + 32400128);          //  6,400,000 B
  unsigned* tmp = (unsigned*)(w + 38800128);    //  6,400,000 B
  int*   M   = (int*)  (w + 45200128);          //    262,144 B [256][256]
  int*   bst = (int*)  (w + 45462272);          //      1,028 B [257]
  // total ~45.5 MB

  k_h1g <<<G1B + NHB, 1024, 0, stream>>>(x, W1, a1s, a1d, h1, ssh1, sd1, receivers, M);
  k_p1s <<<NHB, 1024, 0, stream>>>(receivers, senders, M, tmp, bst);
  k_p2  <<<NBUCK, 1024, 0, stream>>>(bst, tmp, rs, csr);
  k_agg1<<<25000, 256, 0, stream>>>(rs, csr, ssh1, sd1, h1, z);
  k_gemm2<<<1563, 256, 0, stream>>>(z, W2, a2s, a2d, h2, ss2, sd2);
  k_agg2<<<25000, 256, 0, stream>>>(rs, csr, ss2, sd2, h2, out);
}

// Round 2
// 244.423 us; speedup vs baseline: 1.0057x; 1.0057x over previous
//
#include <hip/hip_runtime.h>

#define N_NODES 100000
#define N_EDGES 1600000
#define IN_DIM  128
#define C1      64     // hidden = 4 heads * 16
#define H1      4
#define F1      16
#define C2      16
#define NEG     0.2f
#define EPS_    1e-9f

#define NHB     256            // hist blocks (and matrix columns)
#define EPB     (N_EDGES/NHB)  // 6250 edges per hist/p1 block
#define G1B     391            // gemm1 blocks in fused kernel
#define NBUCK   196            // ceil(100000/512) non-empty buckets

typedef _Float16 half8 __attribute__((ext_vector_type(8)));
typedef _Float16 half4 __attribute__((ext_vector_type(4)));
typedef float float4v __attribute__((ext_vector_type(4)));

__device__ __forceinline__ float lrelu(float x) { return x > 0.f ? x : NEG * x; }

// ================= k_h1g: layer-1 GEMM (MFMA, LDS-built WT1) + bucket hist =================

__global__ __launch_bounds__(1024) void k_h1g(
    const float* __restrict__ x, const float* __restrict__ W1,
    const float* __restrict__ a1s, const float* __restrict__ a1d,
    _Float16* __restrict__ h1, _Float16* __restrict__ ssh, float* __restrict__ sd,
    const int* __restrict__ recv, int* __restrict__ M) {
  __shared__ _Float16 WT1L[80 * 136];   // rows 0-63 W1cat^T, 64-71 fused a-vecs; +8 pad
  __shared__ int hc[NHB];
  int b = blockIdx.x, t = threadIdx.x;

  if (b >= G1B) {                       // ---- histogram part ----
    int hb = b - G1B;
    if (t < NHB) hc[t] = 0;
    __syncthreads();
    int e1 = (hb + 1) * EPB;
    for (int e = hb * EPB + t; e < e1; e += 1024)
      atomicAdd(&hc[recv[e] >> 9], 1);  // LDS atomic
    __syncthreads();
    if (t < NHB) M[t * NHB + hb] = hc[t];
    return;
  }

  // ---- build WT1 in LDS ----
  for (int i = t; i < 80 * 128; i += 1024) {
    int c = i >> 7, k = i & 127;
    float v;
    if (c < 64) v = W1[(c >> 4) * 2048 + k * 16 + (c & 15)];
    else {
      int h = (c - 64) & 3;
      const float* a = (c < 68) ? a1s : a1d;
      float s = 0.f;
      for (int f = 0; f < 16; ++f) s += W1[h * 2048 + k * 16 + f] * a[h * 16 + f];
      v = s;
    }
    WT1L[c * 136 + k] = (_Float16)v;
  }
  __syncthreads();

  int wave = b * 16 + (t >> 6);
  int n0 = wave * 16;
  if (n0 >= N_NODES) return;
  int lane = t & 63;
  int mrow = lane & 15, quad = lane >> 4;
  const float* xrow = x + (size_t)(n0 + mrow) * IN_DIM + quad * 8;
  float4v acc[5];
#pragma unroll
  for (int i = 0; i < 5; ++i) acc[i] = (float4v)(0.f);
#pragma unroll
  for (int kt = 0; kt < 4; ++kt) {
    float4 a0 = *(const float4*)(xrow + kt * 32);
    float4 a1 = *(const float4*)(xrow + kt * 32 + 4);
    half8 af;
    af[0] = (_Float16)a0.x; af[1] = (_Float16)a0.y; af[2] = (_Float16)a0.z; af[3] = (_Float16)a0.w;
    af[4] = (_Float16)a1.x; af[5] = (_Float16)a1.y; af[6] = (_Float16)a1.z; af[7] = (_Float16)a1.w;
#pragma unroll
    for (int i = 0; i < 5; ++i) {
      half8 bf = *(const half8*)(WT1L + (i * 16 + mrow) * 136 + kt * 32 + quad * 8);
      acc[i] = __builtin_amdgcn_mfma_f32_16x16x32_f16(af, bf, acc[i], 0, 0, 0);
    }
  }
#pragma unroll
  for (int i = 0; i < 4; ++i)
#pragma unroll
    for (int r = 0; r < 4; ++r)
      h1[(size_t)(n0 + quad * 4 + r) * C1 + i * 16 + mrow] = (_Float16)acc[i][r];
  if (mrow < 8) {
#pragma unroll
    for (int r = 0; r < 4; ++r) {
      int n = n0 + quad * 4 + r;
      float v = acc[4][r];
      if (mrow < 4) ssh[n * 4 + mrow] = (_Float16)v;
      else          sd[n * 4 + (mrow - 4)] = v;
    }
  }
}

// ================= k_p1s: fused coalesced matrix-scan + edge placement =================

__global__ __launch_bounds__(1024) void k_p1s(
    const int* __restrict__ recv, const int* __restrict__ send,
    const int* __restrict__ M, unsigned* __restrict__ tmp, int* __restrict__ bstart) {
  __shared__ int rsum[NHB], rpart[NHB], rscan[NHB], cur[NHB];
  int blk = blockIdx.x, t = threadIdx.x;
  int wv = t >> 6, l = t & 63;
  for (int pass = 0; pass < 16; ++pass) {     // 16 waves x 16 passes = 256 rows
    int row = pass * 16 + wv;
    int s = 0, p = 0;
#pragma unroll
    for (int c4 = 0; c4 < 4; ++c4) {
      int col = c4 * 64 + l;
      int v = M[row * NHB + col];
      s += v;
      p += (col < blk) ? v : 0;
    }
#pragma unroll
    for (int off = 1; off < 64; off <<= 1) {
      s += __shfl_xor(s, off);
      p += __shfl_xor(p, off);
    }
    if (l == 0) { rsum[row] = s; rpart[row] = p; }
  }
  __syncthreads();
  if (t < 64) {                               // exclusive scan of 256 rowsums
    int a0 = rsum[4 * t], a1 = rsum[4 * t + 1], a2 = rsum[4 * t + 2], a3 = rsum[4 * t + 3];
    int tot = a0 + a1 + a2 + a3, sc = tot;
#pragma unroll
    for (int off = 1; off < 64; off <<= 1) { int u = __shfl_up(sc, off); if (t >= off) sc += u; }
    int ex = sc - tot;
    rscan[4 * t] = ex; rscan[4 * t + 1] = ex + a0;
    rscan[4 * t + 2] = ex + a0 + a1; rscan[4 * t + 3] = ex + a0 + a1 + a2;
  }
  __syncthreads();
  if (t < NHB) cur[t] = rscan[t] + rpart[t];
  if (blk == 0 && t < NHB) bstart[t] = rscan[t];
  if (blk == 0 && t == 0) bstart[NHB] = N_EDGES;
  __syncthreads();
  int e1 = (blk + 1) * EPB;
  for (int e = blk * EPB + t; e < e1; e += 1024) {
    int r = recv[e], s = send[e];
    int pos = atomicAdd(&cur[r >> 9], 1);     // LDS returning atomic
    tmp[pos] = ((unsigned)(r & 511) << 17) | (unsigned)s;
  }
}

// ================= p2: per-bucket counting sort -> rs + csr =================

__global__ __launch_bounds__(1024) void k_p2(
    const int* __restrict__ bstart, const unsigned* __restrict__ tmp,
    int* __restrict__ rs, int* __restrict__ csr) {
  __shared__ int cnt[512];
  __shared__ int wt[8];
  int b = blockIdx.x, t = threadIdx.x;
  int e0 = bstart[b];
  int e1 = bstart[b + 1];
  if (t < 512) cnt[t] = 0;
  __syncthreads();
  for (int e = e0 + t; e < e1; e += 1024)
    atomicAdd(&cnt[tmp[e] >> 17], 1);
  __syncthreads();
  int v = (t < 512) ? cnt[t] : 0;
  int l = t & 63, s = v;
#pragma unroll
  for (int off = 1; off < 64; off <<= 1) { int u = __shfl_up(s, off); if (l >= off) s += u; }
  if (t < 512 && l == 63) wt[t >> 6] = s;
  __syncthreads();
  if (t < 8) {
    int p = wt[t];
#pragma unroll
    for (int off = 1; off < 8; off <<= 1) { int u = __shfl_up(p, off); if (t >= off) p += u; }
    wt[t] = p;
  }
  __syncthreads();
  int base = (t >= 64 && t < 512) ? wt[(t >> 6) - 1] : 0;
  int excl = e0 + base + s - v;
  int idx = b * 512 + t;
  if (t < 512 && idx <= N_NODES) rs[idx] = excl;
  __syncthreads();
  if (t < 512) cnt[t] = excl;
  __syncthreads();
  for (int e = e0 + t; e < e1; e += 1024) {
    unsigned u = tmp[e];
    int pos = atomicAdd(&cnt[u >> 17], 1);
    csr[pos] = (int)(u & 0x1FFFFu);
  }
}

// ================= k_agg1: layer-1 aggregation =================
// R11: 8 lanes/edge (cheap VALU, R10) x 2 independent chains (16 edges in
// flight, R9-proven MLP). csr/rs read-once streams marked nontemporal so the
// per-XCD L2 keeps h1 rows resident instead (h1 refetch dominates FETCH_SIZE).

__global__ __launch_bounds__(256) void k_agg1(
    const int* __restrict__ rs, const int* __restrict__ csr,
    const _Float16* __restrict__ ssh, const float* __restrict__ sdst,
    const _Float16* __restrict__ h1, _Float16* __restrict__ z) {
  int wid = (blockIdx.x * 256 + threadIdx.x) >> 6;
  if (wid >= N_NODES) return;
  int lane = threadIdx.x & 63;
  int g = lane >> 3;          // edge slot 0..7
  int f8 = lane & 7;          // feature block: feats [f8*8, f8*8+8)
  int h = f8 >> 1;            // head for this feature block
  int start = rs[wid], deg = rs[wid + 1] - start;
  float sdh = sdst[wid * 4 + h];
  float acc[8];
#pragma unroll
  for (int i = 0; i < 8; ++i) acc[i] = 0.f;
  float dsum = 0.f;
  const _Float16* hbase = h1 + f8 * 8;
  for (int j0 = 0; j0 < deg; j0 += 16) {
    int jA = j0 + g, jB = j0 + 8 + g;
    int sA = __builtin_nontemporal_load(csr + start + (jA < deg ? jA : 0));
    int sB = __builtin_nontemporal_load(csr + start + (jB < deg ? jB : 0));
    float eA = (float)ssh[sA * 4 + h];
    float eB = (float)ssh[sB * 4 + h];
    half8 hA = *(const half8*)(hbase + (size_t)sA * C1);
    half8 hB = *(const half8*)(hbase + (size_t)sB * C1);
    float alA = (jA < deg) ? __expf(lrelu(eA + sdh)) : 0.f;
    float alB = (jB < deg) ? __expf(lrelu(eB + sdh)) : 0.f;
    dsum += alA + alB;
#pragma unroll
    for (int i = 0; i < 8; ++i)
      acc[i] = fmaf(alA, (float)hA[i], fmaf(alB, (float)hB[i], acc[i]));
  }
#pragma unroll
  for (int off = 8; off <= 32; off <<= 1) {
#pragma unroll
    for (int i = 0; i < 8; ++i) acc[i] += __shfl_xor(acc[i], off);
    dsum += __shfl_xor(dsum, off);
  }
  if (g == 0) {
    float inv = 1.f / (dsum + EPS_);
    half8 o;
#pragma unroll
    for (int i = 0; i < 8; ++i) {
      float v = acc[i] * inv;
      o[i] = (_Float16)(v > 0.f ? v : __expf(v) - 1.f);
    }
    *(half8*)(z + (size_t)wid * C1 + f8 * 8) = o;
  }
}

// ================= k_gemm2: MFMA, WT2 built in LDS (rows 18-31 zero) =================

__global__ __launch_bounds__(256) void k_gemm2(
    const _Float16* __restrict__ z, const float* __restrict__ W2,
    const float* __restrict__ a2s, const float* __restrict__ a2d,
    _Float16* __restrict__ h2, float* __restrict__ ss2, float* __restrict__ sd2) {
  __shared__ _Float16 WT2L[32 * 64];
  int t = threadIdx.x;
  for (int i = t; i < 32 * 64; i += 256) {
    int c = i >> 6, k = i & 63;
    float v = 0.f;
    if (c < 16) v = W2[k * 16 + c];
    else if (c == 16) { for (int f = 0; f < 16; ++f) v += W2[k * 16 + f] * a2s[f]; }
    else if (c == 17) { for (int f = 0; f < 16; ++f) v += W2[k * 16 + f] * a2d[f]; }
    WT2L[i] = (_Float16)v;
  }
  __syncthreads();
  int wave = blockIdx.x * 4 + (t >> 6);
  int n0 = wave * 16;
  if (n0 >= N_NODES) return;
  int lane = t & 63;
  int mrow = lane & 15, quad = lane >> 4;
  float4v acc0 = (float4v)(0.f), acc1 = (float4v)(0.f);
#pragma unroll
  for (int kt = 0; kt < 2; ++kt) {
    half8 af = *(const half8*)(z + (size_t)(n0 + mrow) * C1 + kt * 32 + quad * 8);
    half8 b0 = *(const half8*)(WT2L + (0 * 16 + mrow) * C1 + kt * 32 + quad * 8);
    half8 b1 = *(const half8*)(WT2L + (1 * 16 + mrow) * C1 + kt * 32 + quad * 8);
    acc0 = __builtin_amdgcn_mfma_f32_16x16x32_f16(af, b0, acc0, 0, 0, 0);
    acc1 = __builtin_amdgcn_mfma_f32_16x16x32_f16(af, b1, acc1, 0, 0, 0);
  }
#pragma unroll
  for (int r = 0; r < 4; ++r)
    h2[(size_t)(n0 + quad * 4 + r) * C2 + mrow] = (_Float16)acc0[r];
  if (mrow == 0) {
#pragma unroll
    for (int r = 0; r < 4; ++r) ss2[n0 + quad * 4 + r] = acc1[r];
  } else if (mrow == 1) {
#pragma unroll
    for (int r = 0; r < 4; ++r) sd2[n0 + quad * 4 + r] = acc1[r];
  }
}

// ================= k_agg2: layer-2 aggregation (R9-proven: 32 edges in flight) =================
// R11: reverted from the R10 16-in-flight form, which cost ~10us by halving MLP.
// csr stream nontemporal: keeps h2 (3.2MB) resident in each 4MB XCD L2.

__global__ __launch_bounds__(256) void k_agg2(
    const int* __restrict__ rs, const int* __restrict__ csr,
    const float* __restrict__ ss2, const float* __restrict__ sd2,
    const _Float16* __restrict__ h2, float* __restrict__ out) {
  int wid = (blockIdx.x * 256 + threadIdx.x) >> 6;
  if (wid >= N_NODES) return;
  int lane = threadIdx.x & 63;
  int g = lane >> 2, q = lane & 3;
  int start = rs[wid], deg = rs[wid + 1] - start;
  float sd = sd2[wid];
  float a0 = 0.f, a1 = 0.f, a2 = 0.f, a3 = 0.f, dsum = 0.f;
  for (int j0 = 0; j0 < deg; j0 += 32) {
    int jA = j0 + g, jB = j0 + 16 + g;
    int sA = __builtin_nontemporal_load(csr + start + (jA < deg ? jA : 0));
    int sB = __builtin_nontemporal_load(csr + start + (jB < deg ? jB : 0));
    float eA = ss2[sA], eB = ss2[sB];
    half4 hA = *(const half4*)(h2 + (size_t)sA * C2 + q * 4);
    half4 hB = *(const half4*)(h2 + (size_t)sB * C2 + q * 4);
    float alA = (jA < deg) ? __expf(lrelu(eA + sd)) : 0.f;
    float alB = (jB < deg) ? __expf(lrelu(eB + sd)) : 0.f;
    dsum += alA + alB;
    a0 = fmaf(alA, (float)hA[0], fmaf(alB, (float)hB[0], a0));
    a1 = fmaf(alA, (float)hA[1], fmaf(alB, (float)hB[1], a1));
    a2 = fmaf(alA, (float)hA[2], fmaf(alB, (float)hB[2], a2));
    a3 = fmaf(alA, (float)hA[3], fmaf(alB, (float)hB[3], a3));
  }
#pragma unroll
  for (int off = 4; off <= 32; off <<= 1) {
    a0 += __shfl_xor(a0, off); a1 += __shfl_xor(a1, off);
    a2 += __shfl_xor(a2, off); a3 += __shfl_xor(a3, off);
    dsum += __shfl_xor(dsum, off);
  }
  if (g == 0) {
    float inv = 1.f / (dsum + EPS_);
    float4 o = make_float4(a0 * inv, a1 * inv, a2 * inv, a3 * inv);
    *(float4*)(out + (size_t)wid * C2 + q * 4) = o;
  }
}

// ================= launch: 6 dispatches =================

extern "C" void kernel_launch(void* const* d_in, const int* in_sizes, int n_in,
                              void* d_out, int out_size, void* d_ws, size_t ws_size,
                              hipStream_t stream) {
  const float* x    = (const float*)d_in[0];
  const int* senders   = (const int*)d_in[1];
  const int* receivers = (const int*)d_in[2];
  const float* W1  = (const float*)d_in[3];
  const float* a1s = (const float*)d_in[4];
  const float* a1d = (const float*)d_in[5];
  const float* W2  = (const float*)d_in[6];
  const float* a2s = (const float*)d_in[7];
  const float* a2d = (const float*)d_in[8];
  float* out = (float*)d_out;

  char* w = (char*)d_ws;
  _Float16* h1   = (_Float16*)(w + 0);          // 12,800,000 B [N][64]
  _Float16* z    = (_Float16*)(w + 12800000);   // 12,800,000 B
  _Float16* ssh1 = (_Float16*)(w + 25600000);   //    800,000 B [N][4]
  float* sd1 = (float*)(w + 26400000);          //  1,600,000 B [N][4]
  _Float16* h2   = (_Float16*)(w + 28000000);   //  3,200,000 B [N][16]
  float* ss2 = (float*)(w + 31200000);          //    400,000 B [N]
  float* sd2 = (float*)(w + 31600000);          //    400,000 B [N]
  int*   rs  = (int*)  (w + 32000000);          //    400,128 B [N+1]
  int*   csr = (int*)  (w + 32400128);          //  6,400,000 B
  unsigned* tmp = (unsigned*)(w + 38800128);    //  6,400,000 B
  int*   M   = (int*)  (w + 45200128);          //    262,144 B [256][256]
  int*   bst = (int*)  (w + 45462272);          //      1,028 B [257]
  // total ~45.5 MB

  k_h1g <<<G1B + NHB, 1024, 0, stream>>>(x, W1, a1s, a1d, h1, ssh1, sd1, receivers, M);
  k_p1s <<<NHB, 1024, 0, stream>>>(receivers, senders, M, tmp, bst);
  k_p2  <<<NBUCK, 1024, 0, stream>>>(bst, tmp, rs, csr);
  k_agg1<<<25000, 256, 0, stream>>>(rs, csr, ssh1, sd1, h1, z);
  k_gemm2<<<1563, 256, 0, stream>>>(z, W2, a2s, a2d, h2, ss2, sd2);
  k_agg2<<<25000, 256, 0, stream>>>(rs, csr, ss2, sd2, h2, out);
}

// Round 3
// 234.216 us; speedup vs baseline: 1.0495x; 1.0436x over previous
//
#include <hip/hip_runtime.h>

#define N_NODES 100000
#define N_EDGES 1600000
#define IN_DIM  128
#define C1      64     // hidden = 4 heads * 16
#define H1      4
#define F1      16
#define C2      16
#define NEG     0.2f
#define EPS_    1e-9f

#define NHB     256            // hist blocks (and matrix columns)
#define EPB     (N_EDGES/NHB)  // 6250 edges per hist/p1 block
#define G1B     391            // gemm1 blocks in fused kernel
#define NBUCK   196            // ceil(100000/512) non-empty buckets

typedef _Float16 half8 __attribute__((ext_vector_type(8)));
typedef _Float16 half4 __attribute__((ext_vector_type(4)));
typedef float float4v __attribute__((ext_vector_type(4)));

__device__ __forceinline__ float lrelu(float x) { return x > 0.f ? x : NEG * x; }

// ================= k_h1g: layer-1 GEMM (MFMA, LDS-built WT1) + bucket hist =================

__global__ __launch_bounds__(1024) void k_h1g(
    const float* __restrict__ x, const float* __restrict__ W1,
    const float* __restrict__ a1s, const float* __restrict__ a1d,
    _Float16* __restrict__ h1, _Float16* __restrict__ ssh, float* __restrict__ sd,
    const int* __restrict__ recv, int* __restrict__ M) {
  __shared__ _Float16 WT1L[80 * 136];   // rows 0-63 W1cat^T, 64-71 fused a-vecs; +8 pad
  __shared__ int hc[NHB];
  int b = blockIdx.x, t = threadIdx.x;

  if (b >= G1B) {                       // ---- histogram part ----
    int hb = b - G1B;
    if (t < NHB) hc[t] = 0;
    __syncthreads();
    int e1 = (hb + 1) * EPB;
    for (int e = hb * EPB + t; e < e1; e += 1024)
      atomicAdd(&hc[recv[e] >> 9], 1);  // LDS atomic
    __syncthreads();
    if (t < NHB) M[t * NHB + hb] = hc[t];
    return;
  }

  // ---- build WT1 in LDS ----
  for (int i = t; i < 80 * 128; i += 1024) {
    int c = i >> 7, k = i & 127;
    float v;
    if (c < 64) v = W1[(c >> 4) * 2048 + k * 16 + (c & 15)];
    else {
      int h = (c - 64) & 3;
      const float* a = (c < 68) ? a1s : a1d;
      float s = 0.f;
      for (int f = 0; f < 16; ++f) s += W1[h * 2048 + k * 16 + f] * a[h * 16 + f];
      v = s;
    }
    WT1L[c * 136 + k] = (_Float16)v;
  }
  __syncthreads();

  int wave = b * 16 + (t >> 6);
  int n0 = wave * 16;
  if (n0 >= N_NODES) return;
  int lane = t & 63;
  int mrow = lane & 15, quad = lane >> 4;
  const float* xrow = x + (size_t)(n0 + mrow) * IN_DIM + quad * 8;
  float4v acc[5];
#pragma unroll
  for (int i = 0; i < 5; ++i) acc[i] = (float4v)(0.f);
#pragma unroll
  for (int kt = 0; kt < 4; ++kt) {
    float4 a0 = *(const float4*)(xrow + kt * 32);
    float4 a1 = *(const float4*)(xrow + kt * 32 + 4);
    half8 af;
    af[0] = (_Float16)a0.x; af[1] = (_Float16)a0.y; af[2] = (_Float16)a0.z; af[3] = (_Float16)a0.w;
    af[4] = (_Float16)a1.x; af[5] = (_Float16)a1.y; af[6] = (_Float16)a1.z; af[7] = (_Float16)a1.w;
#pragma unroll
    for (int i = 0; i < 5; ++i) {
      half8 bf = *(const half8*)(WT1L + (i * 16 + mrow) * 136 + kt * 32 + quad * 8);
      acc[i] = __builtin_amdgcn_mfma_f32_16x16x32_f16(af, bf, acc[i], 0, 0, 0);
    }
  }
#pragma unroll
  for (int i = 0; i < 4; ++i)
#pragma unroll
    for (int r = 0; r < 4; ++r)
      h1[(size_t)(n0 + quad * 4 + r) * C1 + i * 16 + mrow] = (_Float16)acc[i][r];
  if (mrow < 8) {
#pragma unroll
    for (int r = 0; r < 4; ++r) {
      int n = n0 + quad * 4 + r;
      float v = acc[4][r];
      if (mrow < 4) ssh[n * 4 + mrow] = (_Float16)v;
      else          sd[n * 4 + (mrow - 4)] = v;
    }
  }
}

// ================= k_p1s: fused coalesced matrix-scan + edge placement =================

__global__ __launch_bounds__(1024) void k_p1s(
    const int* __restrict__ recv, const int* __restrict__ send,
    const int* __restrict__ M, unsigned* __restrict__ tmp, int* __restrict__ bstart) {
  __shared__ int rsum[NHB], rpart[NHB], rscan[NHB], cur[NHB];
  int blk = blockIdx.x, t = threadIdx.x;
  int wv = t >> 6, l = t & 63;
  for (int pass = 0; pass < 16; ++pass) {     // 16 waves x 16 passes = 256 rows
    int row = pass * 16 + wv;
    int s = 0, p = 0;
#pragma unroll
    for (int c4 = 0; c4 < 4; ++c4) {
      int col = c4 * 64 + l;
      int v = M[row * NHB + col];
      s += v;
      p += (col < blk) ? v : 0;
    }
#pragma unroll
    for (int off = 1; off < 64; off <<= 1) {
      s += __shfl_xor(s, off);
      p += __shfl_xor(p, off);
    }
    if (l == 0) { rsum[row] = s; rpart[row] = p; }
  }
  __syncthreads();
  if (t < 64) {                               // exclusive scan of 256 rowsums
    int a0 = rsum[4 * t], a1 = rsum[4 * t + 1], a2 = rsum[4 * t + 2], a3 = rsum[4 * t + 3];
    int tot = a0 + a1 + a2 + a3, sc = tot;
#pragma unroll
    for (int off = 1; off < 64; off <<= 1) { int u = __shfl_up(sc, off); if (t >= off) sc += u; }
    int ex = sc - tot;
    rscan[4 * t] = ex; rscan[4 * t + 1] = ex + a0;
    rscan[4 * t + 2] = ex + a0 + a1; rscan[4 * t + 3] = ex + a0 + a1 + a2;
  }
  __syncthreads();
  if (t < NHB) cur[t] = rscan[t] + rpart[t];
  if (blk == 0 && t < NHB) bstart[t] = rscan[t];
  if (blk == 0 && t == 0) bstart[NHB] = N_EDGES;
  __syncthreads();
  int e1 = (blk + 1) * EPB;
  for (int e = blk * EPB + t; e < e1; e += 1024) {
    int r = recv[e], s = send[e];
    int pos = atomicAdd(&cur[r >> 9], 1);     // LDS returning atomic
    tmp[pos] = ((unsigned)(r & 511) << 17) | (unsigned)s;
  }
}

// ================= p2: per-bucket counting sort -> rs + csr =================

__global__ __launch_bounds__(1024) void k_p2(
    const int* __restrict__ bstart, const unsigned* __restrict__ tmp,
    int* __restrict__ rs, int* __restrict__ csr) {
  __shared__ int cnt[512];
  __shared__ int wt[8];
  int b = blockIdx.x, t = threadIdx.x;
  int e0 = bstart[b];
  int e1 = bstart[b + 1];
  if (t < 512) cnt[t] = 0;
  __syncthreads();
  for (int e = e0 + t; e < e1; e += 1024)
    atomicAdd(&cnt[tmp[e] >> 17], 1);
  __syncthreads();
  int v = (t < 512) ? cnt[t] : 0;
  int l = t & 63, s = v;
#pragma unroll
  for (int off = 1; off < 64; off <<= 1) { int u = __shfl_up(s, off); if (l >= off) s += u; }
  if (t < 512 && l == 63) wt[t >> 6] = s;
  __syncthreads();
  if (t < 8) {
    int p = wt[t];
#pragma unroll
    for (int off = 1; off < 8; off <<= 1) { int u = __shfl_up(p, off); if (t >= off) p += u; }
    wt[t] = p;
  }
  __syncthreads();
  int base = (t >= 64 && t < 512) ? wt[(t >> 6) - 1] : 0;
  int excl = e0 + base + s - v;
  int idx = b * 512 + t;
  if (t < 512 && idx <= N_NODES) rs[idx] = excl;
  __syncthreads();
  if (t < 512) cnt[t] = excl;
  __syncthreads();
  for (int e = e0 + t; e < e1; e += 1024) {
    unsigned u = tmp[e];
    int pos = atomicAdd(&cnt[u >> 17], 1);
    csr[pos] = (int)(u & 0x1FFFFu);
  }
}

// ================= k_agg1: layer-1 aggregation =================
// R12: 8 lanes/edge x 4 independent chains = 32 edges in flight.
//  - E[serial loop trips] drops 1.43 -> 1.03 (deg~Poisson(16)): one latency
//    exposure per node instead of ~1.5.
//  - 4 independent csr->gather dependency trees double outstanding loads/wave.
//  - NT hints removed (R11: +1.3MB fetch, csr lines evicted before reuse).

__global__ __launch_bounds__(256) void k_agg1(
    const int* __restrict__ rs, const int* __restrict__ csr,
    const _Float16* __restrict__ ssh, const float* __restrict__ sdst,
    const _Float16* __restrict__ h1, _Float16* __restrict__ z) {
  int wid = (blockIdx.x * 256 + threadIdx.x) >> 6;
  if (wid >= N_NODES) return;
  int lane = threadIdx.x & 63;
  int g = lane >> 3;          // edge slot 0..7
  int f8 = lane & 7;          // feature block: feats [f8*8, f8*8+8)
  int h = f8 >> 1;            // head for this feature block
  int start = rs[wid], deg = rs[wid + 1] - start;
  float sdh = sdst[wid * 4 + h];
  float acc[8];
#pragma unroll
  for (int i = 0; i < 8; ++i) acc[i] = 0.f;
  float dsum = 0.f;
  const _Float16* hbase = h1 + f8 * 8;
  for (int j0 = 0; j0 < deg; j0 += 32) {
    int jA = j0 + g, jB = j0 + 8 + g, jC = j0 + 16 + g, jD = j0 + 24 + g;
    int sA = csr[start + (jA < deg ? jA : 0)];
    int sB = csr[start + (jB < deg ? jB : 0)];
    int sC = csr[start + (jC < deg ? jC : 0)];
    int sD = csr[start + (jD < deg ? jD : 0)];
    float eA = (float)ssh[sA * 4 + h];
    float eB = (float)ssh[sB * 4 + h];
    float eC = (float)ssh[sC * 4 + h];
    float eD = (float)ssh[sD * 4 + h];
    half8 hA = *(const half8*)(hbase + (size_t)sA * C1);
    half8 hB = *(const half8*)(hbase + (size_t)sB * C1);
    half8 hC = *(const half8*)(hbase + (size_t)sC * C1);
    half8 hD = *(const half8*)(hbase + (size_t)sD * C1);
    float alA = (jA < deg) ? __expf(lrelu(eA + sdh)) : 0.f;
    float alB = (jB < deg) ? __expf(lrelu(eB + sdh)) : 0.f;
    float alC = (jC < deg) ? __expf(lrelu(eC + sdh)) : 0.f;
    float alD = (jD < deg) ? __expf(lrelu(eD + sdh)) : 0.f;
    dsum += (alA + alB) + (alC + alD);
#pragma unroll
    for (int i = 0; i < 8; ++i)
      acc[i] = fmaf(alA, (float)hA[i],
               fmaf(alB, (float)hB[i],
               fmaf(alC, (float)hC[i],
               fmaf(alD, (float)hD[i], acc[i]))));
  }
#pragma unroll
  for (int off = 8; off <= 32; off <<= 1) {
#pragma unroll
    for (int i = 0; i < 8; ++i) acc[i] += __shfl_xor(acc[i], off);
    dsum += __shfl_xor(dsum, off);
  }
  if (g == 0) {
    float inv = 1.f / (dsum + EPS_);
    half8 o;
#pragma unroll
    for (int i = 0; i < 8; ++i) {
      float v = acc[i] * inv;
      o[i] = (_Float16)(v > 0.f ? v : __expf(v) - 1.f);
    }
    *(half8*)(z + (size_t)wid * C1 + f8 * 8) = o;
  }
}

// ================= k_gemm2: MFMA, WT2 built in LDS (rows 18-31 zero) =================

__global__ __launch_bounds__(256) void k_gemm2(
    const _Float16* __restrict__ z, const float* __restrict__ W2,
    const float* __restrict__ a2s, const float* __restrict__ a2d,
    _Float16* __restrict__ h2, float* __restrict__ ss2, float* __restrict__ sd2) {
  __shared__ _Float16 WT2L[32 * 64];
  int t = threadIdx.x;
  for (int i = t; i < 32 * 64; i += 256) {
    int c = i >> 6, k = i & 63;
    float v = 0.f;
    if (c < 16) v = W2[k * 16 + c];
    else if (c == 16) { for (int f = 0; f < 16; ++f) v += W2[k * 16 + f] * a2s[f]; }
    else if (c == 17) { for (int f = 0; f < 16; ++f) v += W2[k * 16 + f] * a2d[f]; }
    WT2L[i] = (_Float16)v;
  }
  __syncthreads();
  int wave = blockIdx.x * 4 + (t >> 6);
  int n0 = wave * 16;
  if (n0 >= N_NODES) return;
  int lane = t & 63;
  int mrow = lane & 15, quad = lane >> 4;
  float4v acc0 = (float4v)(0.f), acc1 = (float4v)(0.f);
#pragma unroll
  for (int kt = 0; kt < 2; ++kt) {
    half8 af = *(const half8*)(z + (size_t)(n0 + mrow) * C1 + kt * 32 + quad * 8);
    half8 b0 = *(const half8*)(WT2L + (0 * 16 + mrow) * C1 + kt * 32 + quad * 8);
    half8 b1 = *(const half8*)(WT2L + (1 * 16 + mrow) * C1 + kt * 32 + quad * 8);
    acc0 = __builtin_amdgcn_mfma_f32_16x16x32_f16(af, b0, acc0, 0, 0, 0);
    acc1 = __builtin_amdgcn_mfma_f32_16x16x32_f16(af, b1, acc1, 0, 0, 0);
  }
#pragma unroll
  for (int r = 0; r < 4; ++r)
    h2[(size_t)(n0 + quad * 4 + r) * C2 + mrow] = (_Float16)acc0[r];
  if (mrow == 0) {
#pragma unroll
    for (int r = 0; r < 4; ++r) ss2[n0 + quad * 4 + r] = acc1[r];
  } else if (mrow == 1) {
#pragma unroll
    for (int r = 0; r < 4; ++r) sd2[n0 + quad * 4 + r] = acc1[r];
  }
}

// ================= k_agg2: layer-2 aggregation (R9-proven form, NT removed) =================

__global__ __launch_bounds__(256) void k_agg2(
    const int* __restrict__ rs, const int* __restrict__ csr,
    const float* __restrict__ ss2, const float* __restrict__ sd2,
    const _Float16* __restrict__ h2, float* __restrict__ out) {
  int wid = (blockIdx.x * 256 + threadIdx.x) >> 6;
  if (wid >= N_NODES) return;
  int lane = threadIdx.x & 63;
  int g = lane >> 2, q = lane & 3;
  int start = rs[wid], deg = rs[wid + 1] - start;
  float sd = sd2[wid];
  float a0 = 0.f, a1 = 0.f, a2 = 0.f, a3 = 0.f, dsum = 0.f;
  for (int j0 = 0; j0 < deg; j0 += 32) {
    int jA = j0 + g, jB = j0 + 16 + g;
    int sA = csr[start + (jA < deg ? jA : 0)];
    int sB = csr[start + (jB < deg ? jB : 0)];
    float eA = ss2[sA], eB = ss2[sB];
    half4 hA = *(const half4*)(h2 + (size_t)sA * C2 + q * 4);
    half4 hB = *(const half4*)(h2 + (size_t)sB * C2 + q * 4);
    float alA = (jA < deg) ? __expf(lrelu(eA + sd)) : 0.f;
    float alB = (jB < deg) ? __expf(lrelu(eB + sd)) : 0.f;
    dsum += alA + alB;
    a0 = fmaf(alA, (float)hA[0], fmaf(alB, (float)hB[0], a0));
    a1 = fmaf(alA, (float)hA[1], fmaf(alB, (float)hB[1], a1));
    a2 = fmaf(alA, (float)hA[2], fmaf(alB, (float)hB[2], a2));
    a3 = fmaf(alA, (float)hA[3], fmaf(alB, (float)hB[3], a3));
  }
#pragma unroll
  for (int off = 4; off <= 32; off <<= 1) {
    a0 += __shfl_xor(a0, off); a1 += __shfl_xor(a1, off);
    a2 += __shfl_xor(a2, off); a3 += __shfl_xor(a3, off);
    dsum += __shfl_xor(dsum, off);
  }
  if (g == 0) {
    float inv = 1.f / (dsum + EPS_);
    float4 o = make_float4(a0 * inv, a1 * inv, a2 * inv, a3 * inv);
    *(float4*)(out + (size_t)wid * C2 + q * 4) = o;
  }
}

// ================= launch: 6 dispatches =================

extern "C" void kernel_launch(void* const* d_in, const int* in_sizes, int n_in,
                              void* d_out, int out_size, void* d_ws, size_t ws_size,
                              hipStream_t stream) {
  const float* x    = (const float*)d_in[0];
  const int* senders   = (const int*)d_in[1];
  const int* receivers = (const int*)d_in[2];
  const float* W1  = (const float*)d_in[3];
  const float* a1s = (const float*)d_in[4];
  const float* a1d = (const float*)d_in[5];
  const float* W2  = (const float*)d_in[6];
  const float* a2s = (const float*)d_in[7];
  const float* a2d = (const float*)d_in[8];
  float* out = (float*)d_out;

  char* w = (char*)d_ws;
  _Float16* h1   = (_Float16*)(w + 0);          // 12,800,000 B [N][64]
  _Float16* z    = (_Float16*)(w + 12800000);   // 12,800,000 B
  _Float16* ssh1 = (_Float16*)(w + 25600000);   //    800,000 B [N][4]
  float* sd1 = (float*)(w + 26400000);          //  1,600,000 B [N][4]
  _Float16* h2   = (_Float16*)(w + 28000000);   //  3,200,000 B [N][16]
  float* ss2 = (float*)(w + 31200000);          //    400,000 B [N]
  float* sd2 = (float*)(w + 31600000);          //    400,000 B [N]
  int*   rs  = (int*)  (w + 32000000);          //    400,128 B [N+1]
  int*   csr = (int*)  (w + 32400128);          //  6,400,000 B
  unsigned* tmp = (unsigned*)(w + 38800128);    //  6,400,000 B
  int*   M   = (int*)  (w + 45200128);          //    262,144 B [256][256]
  int*   bst = (int*)  (w + 45462272);          //      1,028 B [257]
  // total ~45.5 MB

  k_h1g <<<G1B + NHB, 1024, 0, stream>>>(x, W1, a1s, a1d, h1, ssh1, sd1, receivers, M);
  k_p1s <<<NHB, 1024, 0, stream>>>(receivers, senders, M, tmp, bst);
  k_p2  <<<NBUCK, 1024, 0, stream>>>(bst, tmp, rs, csr);
  k_agg1<<<25000, 256, 0, stream>>>(rs, csr, ssh1, sd1, h1, z);
  k_gemm2<<<1563, 256, 0, stream>>>(z, W2, a2s, a2d, h2, ss2, sd2);
  k_agg2<<<25000, 256, 0, stream>>>(rs, csr, ss2, sd2, h2, out);
}